// Round 2
// baseline (267.994 us; speedup 1.0000x reference)
//
#include <hip/hip_runtime.h>

typedef __attribute__((ext_vector_type(8))) __bf16 bf16x8;
typedef __attribute__((ext_vector_type(4))) __bf16 bf16x4;
typedef __attribute__((ext_vector_type(4))) float f32x4;

#define AS1 __attribute__((address_space(1)))
#define AS3 __attribute__((address_space(3)))

__device__ __forceinline__ void gload_lds16(const void* g, void* l) {
  __builtin_amdgcn_global_load_lds((const AS1 void*)g, (AS3 void*)l, 16, 0, 0);
}

// ---------------- prep kernels ----------------

__global__ void cvt_f32_to_bf16(const float* __restrict__ in, __bf16* __restrict__ out, int n4) {
  int i = blockIdx.x * blockDim.x + threadIdx.x;
  int stride = gridDim.x * blockDim.x;
  const float4* in4 = (const float4*)in;
  for (; i < n4; i += stride) {
    float4 v = in4[i];
    bf16x4 o;
    o[0] = (__bf16)v.x; o[1] = (__bf16)v.y; o[2] = (__bf16)v.z; o[3] = (__bf16)v.w;
    *(bf16x4*)(out + 4 * (size_t)i) = o;
  }
}

// in [K][N] f32 -> out [N][K] bf16, scaling columns n < scale_lim by `scale`
__global__ void transpose_f32_to_bf16(const float* __restrict__ in, __bf16* __restrict__ out,
                                      int K, int N, int scale_lim, float scale) {
  __shared__ float tile[32][33];
  int tx = threadIdx.x, ty = threadIdx.y;  // 32 x 8
  int n0 = blockIdx.x * 32, k0 = blockIdx.y * 32;
#pragma unroll
  for (int i = 0; i < 4; i++)
    tile[ty + 8 * i][tx] = in[(size_t)(k0 + ty + 8 * i) * N + n0 + tx];
  __syncthreads();
#pragma unroll
  for (int i = 0; i < 4; i++) {
    int n = n0 + ty + 8 * i;
    float v = tile[tx][ty + 8 * i];
    if (n < scale_lim) v *= scale;
    out[(size_t)n * K + k0 + tx] = (__bf16)v;
  }
}

// ---------------- GEMM: C[M][N] = A[M][K] * BT[N][K]^T + bias ----------------
// 128x128 tile, BK=64, 4 waves (2x2), 16x16x32 bf16 MFMA.
// LDS staged via global_load_lds with pre-swizzled source (chunk ^= row&7).

template <int OUTF32>
__global__ __launch_bounds__(256) void gemm_bt_bf16(
    const __bf16* __restrict__ A, const __bf16* __restrict__ BT,
    const float* __restrict__ bias, int scale_lim,
    __bf16* __restrict__ outb, float* __restrict__ outf,
    int N, int K) {
  __shared__ __align__(16) __bf16 As[128 * 64];
  __shared__ __align__(16) __bf16 Bs[128 * 64];
  const int t = threadIdx.x;
  const int l = t & 63, w = t >> 6;
  const int wr = w >> 1, wc = w & 1;
  const int m0 = blockIdx.y * 128, n0 = blockIdx.x * 128;
  const int l15 = l & 15, lg = l >> 4;

  f32x4 acc[4][4] = {};

  for (int kt = 0; kt < K; kt += 64) {
#pragma unroll
    for (int j = 0; j < 4; j++) {
      int c = j * 256 + t;
      int row = c >> 3, kc = c & 7;
      gload_lds16(A + (size_t)(m0 + row) * K + kt + ((kc ^ (row & 7)) << 3),
                  As + ((j * 256 + w * 64) << 3));
    }
#pragma unroll
    for (int j = 0; j < 4; j++) {
      int c = j * 256 + t;
      int row = c >> 3, kc = c & 7;
      gload_lds16(BT + (size_t)(n0 + row) * K + kt + ((kc ^ (row & 7)) << 3),
                  Bs + ((j * 256 + w * 64) << 3));
    }
    __syncthreads();
#pragma unroll
    for (int ks = 0; ks < 2; ks++) {
      bf16x8 af[4], bfr[4];
#pragma unroll
      for (int fm = 0; fm < 4; fm++) {
        int row = wr * 64 + fm * 16 + l15;
        int off = row * 128 + ((ks * 64 + (lg << 4)) ^ ((row & 7) << 4));
        af[fm] = *(const bf16x8*)((const char*)As + off);
      }
#pragma unroll
      for (int fn = 0; fn < 4; fn++) {
        int row = wc * 64 + fn * 16 + l15;
        int off = row * 128 + ((ks * 64 + (lg << 4)) ^ ((row & 7) << 4));
        bfr[fn] = *(const bf16x8*)((const char*)Bs + off);
      }
#pragma unroll
      for (int fm = 0; fm < 4; fm++)
#pragma unroll
        for (int fn = 0; fn < 4; fn++)
          acc[fm][fn] = __builtin_amdgcn_mfma_f32_16x16x32_bf16(af[fm], bfr[fn], acc[fm][fn], 0, 0, 0);
    }
    __syncthreads();
  }

  // epilogue: C/D layout col = lane&15, row = (lane>>4)*4 + reg  [m89/m91]
#pragma unroll
  for (int fn = 0; fn < 4; fn++) {
    int n = n0 + wc * 64 + fn * 16 + l15;
    float bv = bias[n];
    if (n < scale_lim) bv *= 0.125f;  // attention scale folded into q
#pragma unroll
    for (int fm = 0; fm < 4; fm++) {
      int mbase = m0 + wr * 64 + fm * 16 + (lg << 2);
#pragma unroll
      for (int r = 0; r < 4; r++) {
        float v = acc[fm][fn][r] + bv;
        if (OUTF32)
          outf[(size_t)(mbase + r) * N + n] = v;
        else
          outb[(size_t)(mbase + r) * N + n] = (__bf16)v;
      }
    }
  }
}

// ---------------- flash attention ----------------
// qkv: [B*L][3072] bf16 (q pre-scaled by 0.125). Grid (L/128, B*H), 256 thr.
// Each wave: 32 queries. K-tiles of 64 keys.

__device__ __forceinline__ int swzV(int d) { return (((d & 7) ^ ((d >> 3) & 7)) << 4); }
__device__ __forceinline__ int swzP(int row) { return (((row & 7) ^ ((row >> 3) & 3)) << 4); }

__global__ __launch_bounds__(256) void flash_attn(const __bf16* __restrict__ qkv,
                                                  __bf16* __restrict__ o) {
  __shared__ __align__(16) __bf16 Ks[64 * 64];
  __shared__ __align__(16) __bf16 Vt[64 * 64];   // transposed: [d][key]
  __shared__ __align__(16) __bf16 Ps[4 * 32 * 64];  // wave-private P tiles
  const int t = threadIdx.x;
  const int l = t & 63, w = t >> 6;
  const int l15 = l & 15, lg = l >> 4;
  const int qt = blockIdx.x;
  const int b = blockIdx.y >> 4, h = blockIdx.y & 15;
  const size_t base = (size_t)b * 2048 * 3072 + h * 64;
  const int q0 = qt * 128 + w * 32;

  // Q fragments in registers (A-operand)
  bf16x8 qf[2][2];
#pragma unroll
  for (int fm = 0; fm < 2; fm++)
#pragma unroll
    for (int kf = 0; kf < 2; kf++)
      qf[fm][kf] = *(const bf16x8*)(qkv + base + (size_t)(q0 + fm * 16 + l15) * 3072 +
                                    kf * 32 + (lg << 3));

  f32x4 outa[2][4] = {};
  float m_run[2][4], l_run[2][4];
#pragma unroll
  for (int fm = 0; fm < 2; fm++)
#pragma unroll
    for (int r = 0; r < 4; r++) { m_run[fm][r] = -1e30f; l_run[fm][r] = 0.f; }

  char* PsB = (char*)Ps + w * 4096;  // 32*64*2 bytes per wave

  for (int kt = 0; kt < 2048; kt += 64) {
    __syncthreads();  // protect Ks/Vt from previous iteration's readers
    // stage K (pre-swizzled source -> linear LDS)
#pragma unroll
    for (int j = 0; j < 2; j++) {
      int c = j * 256 + t;
      int row = c >> 3, kc = c & 7;
      gload_lds16(qkv + base + 1024 + (size_t)(kt + row) * 3072 + ((kc ^ (row & 7)) << 3),
                  Ks + ((j * 256 + w * 64) << 3));
    }
    // stage V transposed via registers
#pragma unroll
    for (int p = 0; p < 2; p++) {
      int key = p * 32 + (t >> 3), d0 = (t & 7) << 3;
      bf16x8 vv = *(const bf16x8*)(qkv + base + 2048 + (size_t)(kt + key) * 3072 + d0);
#pragma unroll
      for (int jj = 0; jj < 8; jj++) {
        int d = d0 + jj;
        *(__bf16*)((char*)Vt + d * 128 + ((key * 2) ^ swzV(d))) = vv[jj];
      }
    }
    __syncthreads();

    // S = (q*scale) K^T
    f32x4 s[2][4] = {};
#pragma unroll
    for (int kf = 0; kf < 2; kf++) {
#pragma unroll
      for (int fn = 0; fn < 4; fn++) {
        int row = fn * 16 + l15;
        int off = row * 128 + ((kf * 64 + (lg << 4)) ^ ((row & 7) << 4));
        bf16x8 bk = *(const bf16x8*)((const char*)Ks + off);
#pragma unroll
        for (int fm = 0; fm < 2; fm++)
          s[fm][fn] = __builtin_amdgcn_mfma_f32_16x16x32_bf16(qf[fm][kf], bk, s[fm][fn], 0, 0, 0);
      }
    }

    // online softmax + P write (wave-private LDS)
#pragma unroll
    for (int fm = 0; fm < 2; fm++) {
#pragma unroll
      for (int r = 0; r < 4; r++) {
        float mx = fmaxf(fmaxf(s[fm][0][r], s[fm][1][r]), fmaxf(s[fm][2][r], s[fm][3][r]));
#pragma unroll
        for (int off = 8; off; off >>= 1) mx = fmaxf(mx, __shfl_xor(mx, off));
        float mn = fmaxf(m_run[fm][r], mx);
        float al = __expf(m_run[fm][r] - mn);
        float sum = 0.f;
        int prow = fm * 16 + (lg << 2) + r;
#pragma unroll
        for (int fn = 0; fn < 4; fn++) {
          float p = __expf(s[fm][fn][r] - mn);
          sum += p;
          *(__bf16*)(PsB + prow * 128 + (((fn * 16 + l15) * 2) ^ swzP(prow))) = (__bf16)p;
        }
#pragma unroll
        for (int off = 8; off; off >>= 1) sum += __shfl_xor(sum, off);
        l_run[fm][r] = l_run[fm][r] * al + sum;
        m_run[fm][r] = mn;
#pragma unroll
        for (int fd = 0; fd < 4; fd++) outa[fm][fd][r] *= al;
      }
    }

    asm volatile("s_waitcnt lgkmcnt(0)" ::: "memory");
    __builtin_amdgcn_sched_barrier(0);  // rule #18: keep reads after ds_writes

    // O += P V
#pragma unroll
    for (int km = 0; km < 2; km++) {
      bf16x8 ap[2];
#pragma unroll
      for (int fm = 0; fm < 2; fm++) {
        int row = fm * 16 + l15;
        ap[fm] = *(const bf16x8*)(PsB + row * 128 + ((km * 64 + (lg << 4)) ^ swzP(row)));
      }
#pragma unroll
      for (int fd = 0; fd < 4; fd++) {
        int d = fd * 16 + l15;
        bf16x8 bv = *(const bf16x8*)((const char*)Vt + d * 128 + ((km * 64 + (lg << 4)) ^ swzV(d)));
#pragma unroll
        for (int fm = 0; fm < 2; fm++)
          outa[fm][fd] = __builtin_amdgcn_mfma_f32_16x16x32_bf16(ap[fm], bv, outa[fm][fd], 0, 0, 0);
      }
    }
  }

  // normalize + store merged heads: [B*L][1024] bf16
#pragma unroll
  for (int fm = 0; fm < 2; fm++) {
#pragma unroll
    for (int r = 0; r < 4; r++) {
      float inv = 1.0f / l_run[fm][r];
      int grow = b * 2048 + q0 + fm * 16 + (lg << 2) + r;
#pragma unroll
      for (int fd = 0; fd < 4; fd++) {
        int col = h * 64 + fd * 16 + l15;
        o[(size_t)grow * 1024 + col] = (__bf16)(outa[fm][fd][r] * inv);
      }
    }
  }
}

// ---------------- launch ----------------

extern "C" void kernel_launch(void* const* d_in, const int* in_sizes, int n_in,
                              void* d_out, int out_size, void* d_ws, size_t ws_size,
                              hipStream_t stream) {
  const float* x      = (const float*)d_in[0];
  const float* w_qkv  = (const float*)d_in[1];
  const float* b_qkv  = (const float*)d_in[2];
  const float* w_proj = (const float*)d_in[3];
  const float* b_proj = (const float*)d_in[4];
  float* out = (float*)d_out;

  char* ws = (char*)d_ws;
  __bf16* xb     = (__bf16*)(ws);                 //  8 MiB  [4096][1024]
  __bf16* wqkvT  = (__bf16*)(ws + 8388608);       //  6 MiB  [3072][1024]
  __bf16* wprojT = (__bf16*)(ws + 14680064);      //  2 MiB  [1024][1024]
  __bf16* qkv    = (__bf16*)(ws + 16777216);      // 24 MiB  [4096][3072]
  __bf16* attno  = (__bf16*)(ws + 41943040);      //  8 MiB  [4096][1024]

  cvt_f32_to_bf16<<<2048, 256, 0, stream>>>(x, xb, 4096 * 1024 / 4);
  transpose_f32_to_bf16<<<dim3(96, 32), dim3(32, 8), 0, stream>>>(w_qkv, wqkvT, 1024, 3072,
                                                                  1024, 0.125f);
  transpose_f32_to_bf16<<<dim3(32, 32), dim3(32, 8), 0, stream>>>(w_proj, wprojT, 1024, 1024,
                                                                  0, 1.0f);
  gemm_bt_bf16<0><<<dim3(24, 32), 256, 0, stream>>>(xb, wqkvT, b_qkv, 1024, qkv, nullptr,
                                                    3072, 1024);
  flash_attn<<<dim3(16, 32), 256, 0, stream>>>(qkv, attno);
  gemm_bt_bf16<1><<<dim3(8, 32), 256, 0, stream>>>(attno, wprojT, b_proj, 0, nullptr, out,
                                                   1024, 1024);
}

// Round 3
// 202.526 us; speedup vs baseline: 1.3233x; 1.3233x over previous
//
#include <hip/hip_runtime.h>

typedef __attribute__((ext_vector_type(8))) __bf16 bf16x8;
typedef __attribute__((ext_vector_type(4))) __bf16 bf16x4;
typedef __attribute__((ext_vector_type(4))) float f32x4;
typedef __attribute__((ext_vector_type(16))) float f32x16;

#define AS1 __attribute__((address_space(1)))
#define AS3 __attribute__((address_space(3)))

// 0.125 (1/sqrt(64)) * log2(e) folded into q columns of w_qkv and b_qkv
#define QSCALE 0.18033688011112042f

__device__ __forceinline__ void gload_lds16(const void* g, void* l) {
  __builtin_amdgcn_global_load_lds((const AS1 void*)g, (AS3 void*)l, 16, 0, 0);
}

__device__ __forceinline__ float ex2(float x) { return __builtin_amdgcn_exp2f(x); }

// pack two f32 -> one u32 of 2 bf16 (lo in low half). Compiler emits v_cvt_pk.
__device__ __forceinline__ unsigned pkbf16(float lo, float hi) {
  union { __bf16 h; unsigned short u; } a, b;
  a.h = (__bf16)lo; b.h = (__bf16)hi;
  return (unsigned)a.u | ((unsigned)b.u << 16);
}

// v_permlane32_swap_b32: a' = {a[0:31], b[0:31]}, b' = {a[32:63], b[32:63]}
__device__ __forceinline__ void pls32(unsigned& a, unsigned& b) {
  asm("v_permlane32_swap_b32 %0, %1" : "+v"(a), "+v"(b));
}

union U8 { unsigned u[4]; bf16x8 v; };

// ---------------- prep kernels ----------------

__global__ void cvt_f32_to_bf16(const float* __restrict__ in, __bf16* __restrict__ out, int n4) {
  int i = blockIdx.x * blockDim.x + threadIdx.x;
  int stride = gridDim.x * blockDim.x;
  const float4* in4 = (const float4*)in;
  for (; i < n4; i += stride) {
    float4 v = in4[i];
    bf16x4 o;
    o[0] = (__bf16)v.x; o[1] = (__bf16)v.y; o[2] = (__bf16)v.z; o[3] = (__bf16)v.w;
    *(bf16x4*)(out + 4 * (size_t)i) = o;
  }
}

// in [K][N] f32 -> out [N][K] bf16, scaling columns n < scale_lim by `scale`
__global__ void transpose_f32_to_bf16(const float* __restrict__ in, __bf16* __restrict__ out,
                                      int K, int N, int scale_lim, float scale) {
  __shared__ float tile[32][33];
  int tx = threadIdx.x, ty = threadIdx.y;  // 32 x 8
  int n0 = blockIdx.x * 32, k0 = blockIdx.y * 32;
#pragma unroll
  for (int i = 0; i < 4; i++)
    tile[ty + 8 * i][tx] = in[(size_t)(k0 + ty + 8 * i) * N + n0 + tx];
  __syncthreads();
#pragma unroll
  for (int i = 0; i < 4; i++) {
    int n = n0 + ty + 8 * i;
    float v = tile[tx][ty + 8 * i];
    if (n < scale_lim) v *= scale;
    out[(size_t)n * K + k0 + tx] = (__bf16)v;
  }
}

// ---------------- GEMM: C[M][N] = A[M][K] * BT[N][K]^T + bias ----------------

template <int OUTF32>
__global__ __launch_bounds__(256) void gemm_bt_bf16(
    const __bf16* __restrict__ A, const __bf16* __restrict__ BT,
    const float* __restrict__ bias, int scale_lim,
    __bf16* __restrict__ outb, float* __restrict__ outf,
    int N, int K) {
  __shared__ __align__(16) __bf16 As[128 * 64];
  __shared__ __align__(16) __bf16 Bs[128 * 64];
  const int t = threadIdx.x;
  const int l = t & 63, w = t >> 6;
  const int wr = w >> 1, wc = w & 1;
  const int m0 = blockIdx.y * 128, n0 = blockIdx.x * 128;
  const int l15 = l & 15, lg = l >> 4;

  f32x4 acc[4][4] = {};

  for (int kt = 0; kt < K; kt += 64) {
#pragma unroll
    for (int j = 0; j < 4; j++) {
      int c = j * 256 + t;
      int row = c >> 3, kc = c & 7;
      gload_lds16(A + (size_t)(m0 + row) * K + kt + ((kc ^ (row & 7)) << 3),
                  As + ((j * 256 + w * 64) << 3));
    }
#pragma unroll
    for (int j = 0; j < 4; j++) {
      int c = j * 256 + t;
      int row = c >> 3, kc = c & 7;
      gload_lds16(BT + (size_t)(n0 + row) * K + kt + ((kc ^ (row & 7)) << 3),
                  Bs + ((j * 256 + w * 64) << 3));
    }
    __syncthreads();
#pragma unroll
    for (int ks = 0; ks < 2; ks++) {
      bf16x8 af[4], bfr[4];
#pragma unroll
      for (int fm = 0; fm < 4; fm++) {
        int row = wr * 64 + fm * 16 + l15;
        int off = row * 128 + ((ks * 64 + (lg << 4)) ^ ((row & 7) << 4));
        af[fm] = *(const bf16x8*)((const char*)As + off);
      }
#pragma unroll
      for (int fn = 0; fn < 4; fn++) {
        int row = wc * 64 + fn * 16 + l15;
        int off = row * 128 + ((ks * 64 + (lg << 4)) ^ ((row & 7) << 4));
        bfr[fn] = *(const bf16x8*)((const char*)Bs + off);
      }
      __builtin_amdgcn_s_setprio(1);
#pragma unroll
      for (int fm = 0; fm < 4; fm++)
#pragma unroll
        for (int fn = 0; fn < 4; fn++)
          acc[fm][fn] = __builtin_amdgcn_mfma_f32_16x16x32_bf16(af[fm], bfr[fn], acc[fm][fn], 0, 0, 0);
      __builtin_amdgcn_s_setprio(0);
    }
    __syncthreads();
  }

#pragma unroll
  for (int fn = 0; fn < 4; fn++) {
    int n = n0 + wc * 64 + fn * 16 + l15;
    float bv = bias[n];
    if (n < scale_lim) bv *= QSCALE;
#pragma unroll
    for (int fm = 0; fm < 4; fm++) {
      int mbase = m0 + wr * 64 + fm * 16 + (lg << 2);
#pragma unroll
      for (int r = 0; r < 4; r++) {
        float v = acc[fm][fn][r] + bv;
        if (OUTF32)
          outf[(size_t)(mbase + r) * N + n] = v;
        else
          outb[(size_t)(mbase + r) * N + n] = (__bf16)v;
      }
    }
  }
}

// ---------------- flash attention (swapped-QK^T, in-register softmax) ----------
// qkv: [B*L][3072] bf16, q pre-scaled by 0.125*log2e. Grid (L/128, B*H), 256 thr.
// Wave = 32 queries (one per lane pair). 64-key tiles, 32x32x16 MFMA.
// S^T = mfma(A=K, B=Q^T): lane holds S[key=crow(r,hi)+32ka][query=l31].
// crow(r,hi) = (r&3) + 8*(r>>2) + 4*hi.

__device__ __forceinline__ int swzVb(int d) { return (((d & 7) ^ (d >> 3)) << 4); }

__global__ __launch_bounds__(256, 2) void flash_attn(const __bf16* __restrict__ qkv,
                                                     __bf16* __restrict__ o) {
  __shared__ __align__(16) __bf16 Ks[2][64 * 64];
  __shared__ __align__(16) __bf16 Vt[2][64 * 64];  // [d][key], XOR-swizzled
  const int t = threadIdx.x;
  const int l = t & 63, w = t >> 6;
  const int l31 = l & 31, hi = l >> 5;
  const int b = blockIdx.y >> 4, h = blockIdx.y & 15;
  const size_t base = (size_t)b * 2048 * 3072 + h * 64;
  const __bf16* kqkv = qkv + base + 1024;
  const __bf16* vqkv = qkv + base + 2048;
  const int q0 = blockIdx.x * 128 + w * 32;

  // Q frags (B-operand): lane holds Q[query=l31][d = kf*16 + hi*8 + j]
  bf16x8 qf[4];
#pragma unroll
  for (int kf = 0; kf < 4; kf++)
    qf[kf] = *(const bf16x8*)(qkv + base + (size_t)(q0 + l31) * 3072 + kf * 16 + hi * 8);

  f32x16 oa0 = {}, oa1 = {};
  float m_run = -1e30f, l_run = 0.f;

  const int vkey = t >> 3, vd0 = (t & 7) << 3;

  // prologue: stage tile 0 into buffer 0
  {
#pragma unroll
    for (int j = 0; j < 2; j++) {
      int c = j * 256 + t;
      int row = c >> 3, kc = c & 7;
      gload_lds16(kqkv + (size_t)row * 3072 + ((kc ^ (row & 7)) << 3),
                  (__bf16*)Ks[0] + ((j * 256 + w * 64) << 3));
    }
#pragma unroll
    for (int p = 0; p < 2; p++) {
      int key = p * 32 + vkey;
      bf16x8 vv = *(const bf16x8*)(vqkv + (size_t)key * 3072 + vd0);
#pragma unroll
      for (int jj = 0; jj < 8; jj++) {
        int d = vd0 + jj;
        *(__bf16*)((char*)Vt[0] + d * 128 + ((key * 2) ^ swzVb(d))) = vv[jj];
      }
    }
    __syncthreads();
  }

  int cur = 0;
  for (int it = 0; it < 32; ++it) {
    const char* KsC = (const char*)Ks[cur];
    const char* VtC = (const char*)Vt[cur];
    char* KsN = (char*)Ks[cur ^ 1];
    char* VtN = (char*)Vt[cur ^ 1];
    const int ktn = (it + 1) * 64;

    // prefetch next tile: V into regs, K via global_load_lds
    bf16x8 nv0, nv1;
    if (it < 31) {
      nv0 = *(const bf16x8*)(vqkv + (size_t)(ktn + vkey) * 3072 + vd0);
      nv1 = *(const bf16x8*)(vqkv + (size_t)(ktn + 32 + vkey) * 3072 + vd0);
#pragma unroll
      for (int j = 0; j < 2; j++) {
        int c = j * 256 + t;
        int row = c >> 3, kc = c & 7;
        gload_lds16(kqkv + (size_t)(ktn + row) * 3072 + ((kc ^ (row & 7)) << 3),
                    KsN + (((j * 256 + w * 64) << 3) * 2));
      }
    }

    // ---- S^T = K Q^T ----
    f32x16 s0 = {}, s1 = {};
    __builtin_amdgcn_s_setprio(1);
#pragma unroll
    for (int kf = 0; kf < 4; kf++) {
      int doff = (kf * 32 + hi * 16);
      bf16x8 k0 = *(const bf16x8*)(KsC + l31 * 128 + (doff ^ ((l31 & 7) << 4)));
      bf16x8 k1 = *(const bf16x8*)(KsC + (32 + l31) * 128 + (doff ^ ((l31 & 7) << 4)));
      s0 = __builtin_amdgcn_mfma_f32_32x32x16_bf16(k0, qf[kf], s0, 0, 0, 0);
      s1 = __builtin_amdgcn_mfma_f32_32x32x16_bf16(k1, qf[kf], s1, 0, 0, 0);
    }
    __builtin_amdgcn_s_setprio(0);

    // ---- online softmax, fully in-register (one query per lane) ----
    float mx = s0[0];
#pragma unroll
    for (int r = 1; r < 16; r++) mx = fmaxf(mx, s0[r]);
#pragma unroll
    for (int r = 0; r < 16; r++) mx = fmaxf(mx, s1[r]);
    mx = fmaxf(mx, __shfl_xor(mx, 32));

    if (!__all(mx - m_run <= 8.0f)) {  // defer-max (T13), base-2 units
      float mn = fmaxf(m_run, mx);
      float alpha = ex2(m_run - mn);
      m_run = mn;
      l_run *= alpha;
#pragma unroll
      for (int r = 0; r < 16; r++) {
        float ar = __shfl(alpha, (r & 3) + ((r >> 2) << 3) + (hi << 2));
        oa0[r] *= ar;
        oa1[r] *= ar;
      }
    }

    float sum = 0.f;
#pragma unroll
    for (int r = 0; r < 16; r++) { s0[r] = ex2(s0[r] - m_run); sum += s0[r]; }
#pragma unroll
    for (int r = 0; r < 16; r++) { s1[r] = ex2(s1[r] - m_run); sum += s1[r]; }
    sum += __shfl_xor(sum, 32);
    l_run += sum;

    // write prefetched V (transposed+swizzled) while pack runs
    if (it < 31) {
#pragma unroll
      for (int jj = 0; jj < 8; jj++) {
        int d = vd0 + jj;
        *(__bf16*)(VtN + d * 128 + ((vkey * 2) ^ swzVb(d))) = nv0[jj];
        *(__bf16*)(VtN + d * 128 + (((32 + vkey) * 2) ^ swzVb(d))) = nv1[jj];
      }
    }

    // ---- P -> A-frags via pack + permlane32_swap (T12) ----
    unsigned wk0[8], wk1[8];
#pragma unroll
    for (int j = 0; j < 8; j++) wk0[j] = pkbf16(s0[2 * j], s0[2 * j + 1]);
#pragma unroll
    for (int j = 0; j < 8; j++) wk1[j] = pkbf16(s1[2 * j], s1[2 * j + 1]);

    U8 pa[4];
    {
      unsigned a0 = wk0[0], b0 = wk0[2], a1 = wk0[1], b1 = wk0[3];
      pls32(a0, b0); pls32(a1, b1);
      pa[0].u[0] = a0; pa[0].u[1] = a1; pa[0].u[2] = b0; pa[0].u[3] = b1;
      unsigned a2 = wk0[4], b2 = wk0[6], a3 = wk0[5], b3 = wk0[7];
      pls32(a2, b2); pls32(a3, b3);
      pa[1].u[0] = a2; pa[1].u[1] = a3; pa[1].u[2] = b2; pa[1].u[3] = b3;
      unsigned a4 = wk1[0], b4 = wk1[2], a5 = wk1[1], b5 = wk1[3];
      pls32(a4, b4); pls32(a5, b5);
      pa[2].u[0] = a4; pa[2].u[1] = a5; pa[2].u[2] = b4; pa[2].u[3] = b5;
      unsigned a6 = wk1[4], b6 = wk1[6], a7 = wk1[5], b7 = wk1[7];
      pls32(a6, b6); pls32(a7, b7);
      pa[3].u[0] = a6; pa[3].u[1] = a7; pa[3].u[2] = b6; pa[3].u[3] = b7;
    }

    // ---- O += P V ----
    __builtin_amdgcn_s_setprio(1);
#pragma unroll
    for (int ks = 0; ks < 4; ks++) {
      int koff = ks * 32 + hi * 16;
      bf16x8 v0 = *(const bf16x8*)(VtC + l31 * 128 + (koff ^ swzVb(l31)));
      bf16x8 v1 = *(const bf16x8*)(VtC + (32 + l31) * 128 + (koff ^ swzVb(32 + l31)));
      oa0 = __builtin_amdgcn_mfma_f32_32x32x16_bf16(pa[ks].v, v0, oa0, 0, 0, 0);
      oa1 = __builtin_amdgcn_mfma_f32_32x32x16_bf16(pa[ks].v, v1, oa1, 0, 0, 0);
    }
    __builtin_amdgcn_s_setprio(0);

    __syncthreads();
    cur ^= 1;
  }

  // normalize + store merged heads: [B*L][1024] bf16
  float inv = 1.0f / l_run;
#pragma unroll
  for (int r = 0; r < 16; ++r) {
    int crow = (r & 3) + ((r >> 2) << 3) + (hi << 2);
    float ir = __shfl(inv, crow);
    size_t grow = (size_t)(b * 2048 + q0 + crow);
    o[grow * 1024 + h * 64 + l31] = (__bf16)(oa0[r] * ir);
    o[grow * 1024 + h * 64 + 32 + l31] = (__bf16)(oa1[r] * ir);
  }
}

// ---------------- launch ----------------

extern "C" void kernel_launch(void* const* d_in, const int* in_sizes, int n_in,
                              void* d_out, int out_size, void* d_ws, size_t ws_size,
                              hipStream_t stream) {
  const float* x      = (const float*)d_in[0];
  const float* w_qkv  = (const float*)d_in[1];
  const float* b_qkv  = (const float*)d_in[2];
  const float* w_proj = (const float*)d_in[3];
  const float* b_proj = (const float*)d_in[4];
  float* out = (float*)d_out;

  char* ws = (char*)d_ws;
  __bf16* xb     = (__bf16*)(ws);                 //  8 MiB  [4096][1024]
  __bf16* wqkvT  = (__bf16*)(ws + 8388608);       //  6 MiB  [3072][1024]
  __bf16* wprojT = (__bf16*)(ws + 14680064);      //  2 MiB  [1024][1024]
  __bf16* qkv    = (__bf16*)(ws + 16777216);      // 24 MiB  [4096][3072]
  __bf16* attno  = (__bf16*)(ws + 41943040);      //  8 MiB  [4096][1024]

  cvt_f32_to_bf16<<<2048, 256, 0, stream>>>(x, xb, 4096 * 1024 / 4);
  transpose_f32_to_bf16<<<dim3(96, 32), dim3(32, 8), 0, stream>>>(w_qkv, wqkvT, 1024, 3072,
                                                                  1024, QSCALE);
  transpose_f32_to_bf16<<<dim3(32, 32), dim3(32, 8), 0, stream>>>(w_proj, wprojT, 1024, 1024,
                                                                  0, 1.0f);
  gemm_bt_bf16<0><<<dim3(24, 32), 256, 0, stream>>>(xb, wqkvT, b_qkv, 1024, qkv, nullptr,
                                                    3072, 1024);
  flash_attn<<<dim3(16, 32), 256, 0, stream>>>(qkv, attno);
  gemm_bt_bf16<1><<<dim3(8, 32), 256, 0, stream>>>(attno, wprojT, b_proj, 0, nullptr, out,
                                                   1024, 1024);
}